// Round 9
// baseline (596.267 us; speedup 1.0000x reference)
//
#include <hip/hip_runtime.h>
#include <math.h>

#define LOG2E 1.4426950408889634f

typedef __attribute__((ext_vector_type(8))) __bf16 bf16x8_t;
typedef __attribute__((ext_vector_type(8))) short short8_t;
typedef __attribute__((ext_vector_type(4))) short short4_t;
typedef __attribute__((ext_vector_type(4))) float f32x4;

static __device__ __forceinline__ short f2bf(float f){
    unsigned u = __builtin_bit_cast(unsigned, f);
    unsigned r = (u + 0x7fffu + ((u >> 16) & 1u)) >> 16;
    return (short)r;
}
static __device__ __forceinline__ float bf2f(short s){
    return __builtin_bit_cast(float, (unsigned)((unsigned short)s) << 16);
}

static __device__ __forceinline__ f32x4 mfma16(short8_t a, short8_t b, f32x4 c){
    return __builtin_amdgcn_mfma_f32_16x16x32_bf16(
        __builtin_bit_cast(bf16x8_t, a), __builtin_bit_cast(bf16x8_t, b), c, 0, 0, 0);
}

// xor-lane16 within 32-lane halves (BitMode swizzle), xor-lane32 via bpermute
static __device__ __forceinline__ float swz16(float v){
    return __builtin_bit_cast(float,
        __builtin_amdgcn_ds_swizzle(__builtin_bit_cast(int, v), 0x401F));
}
static __device__ __forceinline__ float bperm32(int addr, float v){
    return __builtin_bit_cast(float,
        __builtin_amdgcn_ds_bpermute(addr, __builtin_bit_cast(int, v)));
}

// ---------- K1: weights -> bf16, transposed to [mat][d][c], coalesced via LDS tile ----------
__global__ __launch_bounds__(256) void prep_w(const float* __restrict__ w0,
    const float* __restrict__ w1, const float* __restrict__ w2,
    const float* __restrict__ w3, short* __restrict__ wT)
{
    __shared__ float T[64 * 65];
    const int mat = blockIdx.x >> 4, tile = blockIdx.x & 15;
    const int c0 = (tile >> 2) * 64, d0 = (tile & 3) * 64;
    const float* src = mat == 0 ? w0 : mat == 1 ? w1 : mat == 2 ? w2 : w3;
    const int t = threadIdx.x;
    #pragma unroll
    for (int i = 0; i < 4; i++){
        int r = (t >> 4) + i * 16, c4 = (t & 15) * 4;
        f32x4 v = *(const f32x4*)(src + (size_t)(c0 + r) * 256 + d0 + c4);
        #pragma unroll
        for (int j = 0; j < 4; j++) T[r * 65 + c4 + j] = v[j];
    }
    __syncthreads();
    int drow = t >> 2, cb = (t & 3) * 16;
    short tmp[16];
    #pragma unroll
    for (int j = 0; j < 16; j++) tmp[j] = f2bf(T[(cb + j) * 65 + drow]);
    short* dst = wT + (size_t)mat * 65536 + (size_t)(d0 + drow) * 256 + c0 + cb;
    *(short8_t*)dst = *(short8_t*)tmp;
    *(short8_t*)(dst + 8) = *(short8_t*)(tmp + 8);
}

// ---------- K2: per-pixel GroupNorm (G=32, 8 ch/group), write hn (B, m~=w*64+h, C) bf16 ----------
__global__ __launch_bounds__(256) void gn_kernel(const float* __restrict__ x,
    const float* __restrict__ gnw, const float* __restrict__ gnb,
    short* __restrict__ hn)
{
    int flat = blockIdx.x * 256 + threadIdx.x;
    int n = flat & 4095, g = (flat >> 12) & 31, b = flat >> 17;
    const float* xp = x + (size_t)(b * 256 + g * 8) * 4096 + n;
    float v[8], s = 0.f, s2 = 0.f;
    #pragma unroll
    for (int k = 0; k < 8; k++){ float t = xp[(size_t)k * 4096]; v[k] = t; s += t; s2 += t * t; }
    float mean = s * 0.125f;
    float var  = s2 * 0.125f - mean * mean;
    float inv  = rsqrtf(var + 1e-6f);
    int h = n >> 6, w = n & 63, m = w * 64 + h;
    short o[8];
    #pragma unroll
    for (int k = 0; k < 8; k++)
        o[k] = f2bf((v[k] - mean) * inv * gnw[g * 8 + k] + gnb[g * 8 + k]);
    *(short8_t*)(hn + (size_t)(b * 4096 + m) * 256 + g * 8) = *(short8_t*)o;
}

// ---------- K3: QKV GEMM. Q row-major (pre-scaled 1/16); K,V fragment-major. ----------
// Kf[(b,kb64,kc,ks,lane,8)]: lane holds key kc*16+(lane&15), ch ks*32+(lane>>4)*8+j.
// Vf2[(b,kbd,kc,cht,lane,8)]: lane holds ch cht*16+(lane&15); j<4: key kbd*128+kc*16+(lane>>4)*4+j,
//                             j>=4: key kbd*128+64+kc*16+(lane>>4)*4+(j-4).  (K=32 PV permutation)
__global__ __launch_bounds__(256) void qkv_gemm(const short* __restrict__ hn,
    const short* __restrict__ wT, const float* __restrict__ bq,
    const float* __restrict__ bk, const float* __restrict__ bv,
    short* __restrict__ Q, short* __restrict__ Kf, short* __restrict__ Vf)
{
    __shared__ short As[64 * 72];
    __shared__ short Bs[64 * 72];
    __shared__ float CT[64 * 65];

    const int tid = threadIdx.x;
    const int m0 = blockIdx.x * 64;
    const int by = blockIdx.y;
    const int mat = by >> 2;                 // 0=Q 1=K 2=V
    const int d0 = (by & 3) * 64;
    const short* w = wT + mat * 65536;
    const float* bias = mat == 0 ? bq : mat == 1 ? bk : bv;

    const int wv = tid >> 6, lane = tid & 63;
    const int wrow = (wv >> 1) * 32, wcol = (wv & 1) * 32;
    const int lrow = lane & 15, lq = lane >> 4;

    f32x4 acc[2][2] = {};

    for (int k0 = 0; k0 < 256; k0 += 64){
        __syncthreads();
        #pragma unroll
        for (int i = 0; i < 2; i++){
            int idx = tid + i * 256, r = idx >> 3, c = (idx & 7) * 8;
            *(short8_t*)&As[r * 72 + c] = *(const short8_t*)(hn + (size_t)(m0 + r) * 256 + k0 + c);
            *(short8_t*)&Bs[r * 72 + c] = *(const short8_t*)(w  + (size_t)(d0 + r) * 256 + k0 + c);
        }
        __syncthreads();
        #pragma unroll
        for (int kk = 0; kk < 2; kk++){
            int off = kk * 32 + lq * 8;
            short8_t a0  = *(short8_t*)&As[(wrow + lrow) * 72 + off];
            short8_t a1  = *(short8_t*)&As[(wrow + 16 + lrow) * 72 + off];
            short8_t b0v = *(short8_t*)&Bs[(wcol + lrow) * 72 + off];
            short8_t b1v = *(short8_t*)&Bs[(wcol + 16 + lrow) * 72 + off];
            acc[0][0] = mfma16(a0, b0v, acc[0][0]);
            acc[0][1] = mfma16(a0, b1v, acc[0][1]);
            acc[1][0] = mfma16(a1, b0v, acc[1][0]);
            acc[1][1] = mfma16(a1, b1v, acc[1][1]);
        }
    }

    const int b = m0 >> 12, kb64 = (m0 & 4095) >> 6;

    if (mat == 0){
        #pragma unroll
        for (int i = 0; i < 2; i++)
          #pragma unroll
          for (int j = 0; j < 2; j++)
            #pragma unroll
            for (int r = 0; r < 4; r++){
                int row = wrow + i * 16 + lq * 4 + r;
                int col = wcol + j * 16 + lrow;
                Q[(size_t)(m0 + row) * 256 + d0 + col] = f2bf((acc[i][j][r] + bias[d0 + col]) * 0.0625f);
            }
    } else if (mat == 1){
        // CT[key][ch]
        #pragma unroll
        for (int i = 0; i < 2; i++)
          #pragma unroll
          for (int j = 0; j < 2; j++)
            #pragma unroll
            for (int r = 0; r < 4; r++){
                int row = wrow + i * 16 + lq * 4 + r;
                int col = wcol + j * 16 + lrow;
                CT[row * 65 + col] = acc[i][j][r] + bias[d0 + col];
            }
        __syncthreads();
        int key = tid >> 2, c16 = (tid & 3) * 16;
        int kc = key >> 4, l15 = key & 15;
        #pragma unroll
        for (int half = 0; half < 2; half++){
            int ch0 = c16 + half * 8;
            int ks = (d0 + ch0) >> 5, lqf = (ch0 & 31) >> 3;
            short tmp[8];
            #pragma unroll
            for (int j = 0; j < 8; j++) tmp[j] = f2bf(CT[key * 65 + ch0 + j]);
            size_t base = ((((size_t)(b * 64 + kb64)) * 4 + kc) * 8 + ks) * 512 + (lqf * 16 + l15) * 8;
            *(short8_t*)(Kf + base) = *(short8_t*)tmp;
        }
    } else {
        // CT[ch][key]
        #pragma unroll
        for (int i = 0; i < 2; i++)
          #pragma unroll
          for (int j = 0; j < 2; j++)
            #pragma unroll
            for (int r = 0; r < 4; r++){
                int row = wrow + i * 16 + lq * 4 + r;
                int col = wcol + j * 16 + lrow;
                CT[col * 65 + row] = acc[i][j][r] + bias[d0 + col];
            }
        __syncthreads();
        const int kbd = kb64 >> 1, parity = kb64 & 1;
        const int cht_l = tid >> 6, lane_s = tid & 63;
        const int l15s = lane_s & 15, lg4s = lane_s >> 4;
        const int cht = (d0 >> 4) + cht_l;
        #pragma unroll
        for (int kc = 0; kc < 4; kc++){
            short tmp[4];
            #pragma unroll
            for (int j = 0; j < 4; j++)
                tmp[j] = f2bf(CT[(cht_l * 16 + l15s) * 65 + kc * 16 + lg4s * 4 + j]);
            size_t base = (size_t)b * 1048576 + (size_t)kbd * 32768 + kc * 8192
                        + cht * 512 + lane_s * 8 + parity * 4;
            *(short4_t*)(Vf + base) = *(short4_t*)tmp;
        }
    }
}

// ---------- K4: barrier-free flash attention, merged pair-softmax, bf16 combine ----------
// 1024 blocks of 256 threads (4 waves). Each wave runs an independent online-softmax
// chain over its 16-key strips (S^T: stats per lane-column), O^T over all 256 ch.
// bf16 LO staging -> 34 KB LDS -> 4 blocks/CU; quad w-mapping balances resident sets.
__global__ __launch_bounds__(256, 4) void attn_kernel(const short* __restrict__ Q,
    const short* __restrict__ Kf, const short* __restrict__ Vf,
    short* __restrict__ hb)
{
    __shared__ float mls[4][16][2];
    __shared__ short LOs[4][16][264];    // [kc][q][ch] bf16, padded (33 KB)

    const int tid = threadIdx.x, lane = tid & 63, kc = tid >> 6;
    const int l15 = lane & 15, lg4 = lane >> 4;
    const int a32 = ((lane ^ 32) << 2);

    const int id = blockIdx.x;
    const int qd = id >> 8, c = id & 255;
    const int w6 = c >> 2, hh = (c >> 1) & 1, rg = c & 1;
    const int b  = qd;
    const int w  = (qd & 1) ? 63 - w6 : w6;
    const int q0 = w * 64 + hh * 32 + rg * 16;

    const short* Kb = Kf + (size_t)b * 1048576 + kc * 4096 + lane * 8;   // +kb*16384 +ks*512
    const short* Vb = Vf + (size_t)b * 1048576 + kc * 8192 + lane * 8;   // +kbd*32768 +cht*512

    // Q as B-fragment (pre-scaled): lane holds Q[q0+l15][ks*32+lg4*8 ..+8]
    short8_t qf[8];
    {
        const short* qp = Q + ((size_t)b * 4096 + q0 + l15) * 256;
        #pragma unroll
        for (int ks = 0; ks < 8; ks++)
            qf[ks] = *(const short8_t*)(qp + ks * 32 + lg4 * 8);
    }

    f32x4 oacc[16] = {};                 // O^T partial: 16 ch-tiles x f32x4
    float m_run = -1e30f, l_run = 0.f;

    short8_t kcur[8], knext[8];
    #pragma unroll
    for (int ks = 0; ks < 8; ks++)
        kcur[ks] = *(const short8_t*)(Kb + ks * 512);

    for (int kb = 0; kb <= w; kb += 2){
        const bool has_odd = (kb + 1 <= w);
        if (has_odd){
            const short* kit = Kb + (size_t)(kb + 1) * 16384;
            #pragma unroll
            for (int ks = 0; ks < 8; ks++)
                knext[ks] = *(const short8_t*)(kit + ks * 512);
        }
        // even strip: S^T = K (A) x Q (B)
        f32x4 st = {};
        #pragma unroll
        for (int ks = 0; ks < 8; ks++) st = mfma16(kcur[ks], qf[ks], st);

        // refill kcur for next pair (after st consumed kcur)
        if (kb + 2 <= w){
            const short* kit = Kb + (size_t)(kb + 2) * 16384;
            #pragma unroll
            for (int ks = 0; ks < 8; ks++)
                kcur[ks] = *(const short8_t*)(kit + ks * 512);
        }

        // odd strip (independent MFMA chain -> ILP with even)
        f32x4 st2 = { -1e30f, -1e30f, -1e30f, -1e30f };
        if (has_odd){
            f32x4 z = {};
            #pragma unroll
            for (int ks = 0; ks < 8; ks++) z = mfma16(knext[ks], qf[ks], z);
            st2 = z;
        }

        // ONE merged softmax update for the 32-key pair
        float tmax = fmaxf(fmaxf(fmaxf(st[0], st[1]), fmaxf(st[2], st[3])),
                           fmaxf(fmaxf(st2[0], st2[1]), fmaxf(st2[2], st2[3])));
        tmax = fmaxf(tmax, swz16(tmax));
        tmax = fmaxf(tmax, bperm32(a32, tmax));
        float m_new = fmaxf(m_run, tmax);
        float alpha = exp2f((m_run - m_new) * LOG2E);
        m_run = m_new;

        f32x4 p_e, p_o;
        #pragma unroll
        for (int r = 0; r < 4; r++){
            p_e[r] = exp2f((st[r]  - m_new) * LOG2E);
            p_o[r] = exp2f((st2[r] - m_new) * LOG2E);
        }
        float tsum = ((p_e[0] + p_e[1]) + (p_e[2] + p_e[3]))
                   + ((p_o[0] + p_o[1]) + (p_o[2] + p_o[3]));
        tsum += swz16(tsum);
        tsum += bperm32(a32, tsum);
        l_run = l_run * alpha + tsum;

        // pack P^T pair as B-fragment (K=32, key-permuted to match Vf2)
        short pb[8];
        #pragma unroll
        for (int r = 0; r < 4; r++){ pb[r] = f2bf(p_e[r]); pb[4 + r] = f2bf(p_o[r]); }
        short8_t pbf = *(short8_t*)pb;

        // PV: O^T[cht] = alpha*O^T[cht] + V^T-frag x P^T
        const short* vit = Vb + (size_t)(kb >> 1) * 32768;
        #pragma unroll
        for (int cht = 0; cht < 16; cht++){
            short8_t vfr = *(const short8_t*)(vit + cht * 512);
            f32x4 t = oacc[cht];
            #pragma unroll
            for (int r = 0; r < 4; r++) t[r] *= alpha;
            oacc[cht] = mfma16(vfr, pbf, t);
        }
    }

    // ---- combine the 4 kc partials ----
    if (lg4 == 0){ mls[kc][l15][0] = m_run; mls[kc][l15][1] = l_run; }
    __syncthreads();
    float m0v = mls[0][l15][0], m1v = mls[1][l15][0], m2v = mls[2][l15][0], m3v = mls[3][l15][0];
    float mstar = fmaxf(fmaxf(m0v, m1v), fmaxf(m2v, m3v));
    float Lsum = mls[0][l15][1] * exp2f((m0v - mstar) * LOG2E)
               + mls[1][l15][1] * exp2f((m1v - mstar) * LOG2E)
               + mls[2][l15][1] * exp2f((m2v - mstar) * LOG2E)
               + mls[3][l15][1] * exp2f((m3v - mstar) * LOG2E);
    float sc = exp2f((m_run - mstar) * LOG2E);
    #pragma unroll
    for (int cht = 0; cht < 16; cht++){
        short t4[4];
        #pragma unroll
        for (int r = 0; r < 4; r++) t4[r] = f2bf(oacc[cht][r] * sc);
        *(short4_t*)&LOs[kc][l15][cht * 16 + lg4 * 4] = *(short4_t*)t4;
    }
    __syncthreads();
    // sum across kc; wave kc handles ch quarter kc*64..+64; lane: q=l15, ch0=kc*64+lg4*16
    {
        const int ch0 = kc * 64 + lg4 * 16;
        float inv = 1.f / Lsum;
        short tmp[16];
        #pragma unroll
        for (int c8 = 0; c8 < 2; c8++){
            short8_t a0 = *(const short8_t*)&LOs[0][l15][ch0 + c8 * 8];
            short8_t a1 = *(const short8_t*)&LOs[1][l15][ch0 + c8 * 8];
            short8_t a2 = *(const short8_t*)&LOs[2][l15][ch0 + c8 * 8];
            short8_t a3 = *(const short8_t*)&LOs[3][l15][ch0 + c8 * 8];
            #pragma unroll
            for (int j = 0; j < 8; j++){
                float s = (bf2f(a0[j]) + bf2f(a1[j])) + (bf2f(a2[j]) + bf2f(a3[j]));
                tmp[c8 * 8 + j] = f2bf(s * inv);
            }
        }
        const int h = hh * 32 + rg * 16 + l15;
        short* dst = hb + ((size_t)b * 4096 + h * 64 + w) * 256 + ch0;
        *(short8_t*)dst = *(short8_t*)tmp;
        *(short8_t*)(dst + 8) = *(short8_t*)(tmp + 8);
    }
}

// ---------- K5: final proj + bias + residual, coalesced f32 store to (B,C,H,W) ----------
__global__ __launch_bounds__(256) void final_gemm(const short* __restrict__ hbuf,
    const short* __restrict__ wT3, const float* __restrict__ b3,
    const float* __restrict__ x, float* __restrict__ out)
{
    __shared__ short As[64 * 72];
    __shared__ short Bs[64 * 72];
    __shared__ float CT[64 * 65];

    const int tid = threadIdx.x;
    const int m0 = blockIdx.x * 64;
    const int d0 = blockIdx.y * 64;
    const int wv = tid >> 6, lane = tid & 63;
    const int wrow = (wv >> 1) * 32, wcol = (wv & 1) * 32;
    const int lrow = lane & 15, lq = lane >> 4;

    f32x4 acc[2][2] = {};
    for (int k0 = 0; k0 < 256; k0 += 64){
        __syncthreads();
        #pragma unroll
        for (int i = 0; i < 2; i++){
            int idx = tid + i * 256, r = idx >> 3, c = (idx & 7) * 8;
            *(short8_t*)&As[r * 72 + c] = *(const short8_t*)(hbuf + (size_t)(m0 + r) * 256 + k0 + c);
            *(short8_t*)&Bs[r * 72 + c] = *(const short8_t*)(wT3 + (size_t)(d0 + r) * 256 + k0 + c);
        }
        __syncthreads();
        #pragma unroll
        for (int kk = 0; kk < 2; kk++){
            int off = kk * 32 + lq * 8;
            short8_t a0  = *(short8_t*)&As[(wrow + lrow) * 72 + off];
            short8_t a1  = *(short8_t*)&As[(wrow + 16 + lrow) * 72 + off];
            short8_t b0v = *(short8_t*)&Bs[(wcol + lrow) * 72 + off];
            short8_t b1v = *(short8_t*)&Bs[(wcol + 16 + lrow) * 72 + off];
            acc[0][0] = mfma16(a0, b0v, acc[0][0]);
            acc[0][1] = mfma16(a0, b1v, acc[0][1]);
            acc[1][0] = mfma16(a1, b0v, acc[1][0]);
            acc[1][1] = mfma16(a1, b1v, acc[1][1]);
        }
    }
    #pragma unroll
    for (int i = 0; i < 2; i++)
      #pragma unroll
      for (int j = 0; j < 2; j++)
        #pragma unroll
        for (int r = 0; r < 4; r++){
            int row = wrow + i * 16 + lq * 4 + r;
            int col = wcol + j * 16 + lrow;
            CT[col * 65 + row] = acc[i][j][r] + b3[d0 + col];
        }
    __syncthreads();
    int b = m0 >> 12, n0 = m0 & 4095, hrow = n0 >> 6;
    int dr = tid >> 2, wc = (tid & 3) * 16;
    size_t base = ((size_t)(b * 256 + d0 + dr) * 64 + hrow) * 64 + wc;
    const f32x4* xp = (const f32x4*)(x + base);
    f32x4* op = (f32x4*)(out + base);
    #pragma unroll
    for (int q = 0; q < 4; q++){
        f32x4 xv = xp[q], o;
        #pragma unroll
        for (int j = 0; j < 4; j++) o[j] = xv[j] + CT[dr * 65 + wc + q * 4 + j];
        op[q] = o;
    }
}

extern "C" void kernel_launch(void* const* d_in, const int* in_sizes, int n_in,
                              void* d_out, int out_size, void* d_ws, size_t ws_size,
                              hipStream_t stream)
{
    const float* x   = (const float*)d_in[0];
    const float* gnw = (const float*)d_in[1];
    const float* gnb = (const float*)d_in[2];
    const float* w0  = (const float*)d_in[3];
    const float* b0  = (const float*)d_in[4];
    const float* w1  = (const float*)d_in[5];
    const float* b1  = (const float*)d_in[6];
    const float* w2  = (const float*)d_in[7];
    const float* b2  = (const float*)d_in[8];
    const float* w3  = (const float*)d_in[9];
    const float* b3  = (const float*)d_in[10];
    float* out = (float*)d_out;

    char* ws = (char*)d_ws;
    short* wT  = (short*)(ws);                  // 512 KB
    short* hn  = (short*)(ws + 524288);         // 8 MB
    short* Qb  = (short*)(ws + 8912896);        // 8 MB
    short* Kfb = (short*)(ws + 17301504);       // frag-major K, 8 MB
    short* Vfb = (short*)(ws + 25690112);       // frag-major V (K=32 perm), 8 MB
    short* hb  = (short*)(ws + 34078720);       // (B, n, C) 8 MB

    prep_w   <<<64, 256, 0, stream>>>(w0, w1, w2, w3, wT);
    gn_kernel<<<2048, 256, 0, stream>>>(x, gnw, gnb, hn);
    qkv_gemm <<<dim3(256, 12), 256, 0, stream>>>(hn, wT, b0, b1, b2, Qb, Kfb, Vfb);
    attn_kernel<<<1024, 256, 0, stream>>>(Qb, Kfb, Vfb, hb);
    final_gemm<<<dim3(256, 4), 256, 0, stream>>>(hb, wT + 3 * 65536, b3, x, out);
}

// Round 10
// 207.882 us; speedup vs baseline: 2.8683x; 2.8683x over previous
//
#include <hip/hip_runtime.h>
#include <math.h>

#define LOG2E 1.4426950408889634f

typedef __attribute__((ext_vector_type(8))) __bf16 bf16x8_t;
typedef __attribute__((ext_vector_type(8))) short short8_t;
typedef __attribute__((ext_vector_type(4))) short short4_t;
typedef __attribute__((ext_vector_type(4))) float f32x4;

static __device__ __forceinline__ short f2bf(float f){
    unsigned u = __builtin_bit_cast(unsigned, f);
    unsigned r = (u + 0x7fffu + ((u >> 16) & 1u)) >> 16;
    return (short)r;
}
static __device__ __forceinline__ float bf2f(short s){
    return __builtin_bit_cast(float, (unsigned)((unsigned short)s) << 16);
}

static __device__ __forceinline__ f32x4 mfma16(short8_t a, short8_t b, f32x4 c){
    return __builtin_amdgcn_mfma_f32_16x16x32_bf16(
        __builtin_bit_cast(bf16x8_t, a), __builtin_bit_cast(bf16x8_t, b), c, 0, 0, 0);
}

// xor-lane16 within 32-lane halves (BitMode swizzle), xor-lane32 via bpermute
static __device__ __forceinline__ float swz16(float v){
    return __builtin_bit_cast(float,
        __builtin_amdgcn_ds_swizzle(__builtin_bit_cast(int, v), 0x401F));
}
static __device__ __forceinline__ float bperm32(int addr, float v){
    return __builtin_bit_cast(float,
        __builtin_amdgcn_ds_bpermute(addr, __builtin_bit_cast(int, v)));
}

// ---------- K1: weights -> bf16, transposed to [mat][d][c], coalesced via LDS tile ----------
__global__ __launch_bounds__(256) void prep_w(const float* __restrict__ w0,
    const float* __restrict__ w1, const float* __restrict__ w2,
    const float* __restrict__ w3, short* __restrict__ wT)
{
    __shared__ float T[64 * 65];
    const int mat = blockIdx.x >> 4, tile = blockIdx.x & 15;
    const int c0 = (tile >> 2) * 64, d0 = (tile & 3) * 64;
    const float* src = mat == 0 ? w0 : mat == 1 ? w1 : mat == 2 ? w2 : w3;
    const int t = threadIdx.x;
    #pragma unroll
    for (int i = 0; i < 4; i++){
        int r = (t >> 4) + i * 16, c4 = (t & 15) * 4;
        f32x4 v = *(const f32x4*)(src + (size_t)(c0 + r) * 256 + d0 + c4);
        #pragma unroll
        for (int j = 0; j < 4; j++) T[r * 65 + c4 + j] = v[j];
    }
    __syncthreads();
    int drow = t >> 2, cb = (t & 3) * 16;
    short tmp[16];
    #pragma unroll
    for (int j = 0; j < 16; j++) tmp[j] = f2bf(T[(cb + j) * 65 + drow]);
    short* dst = wT + (size_t)mat * 65536 + (size_t)(d0 + drow) * 256 + c0 + cb;
    *(short8_t*)dst = *(short8_t*)tmp;
    *(short8_t*)(dst + 8) = *(short8_t*)(tmp + 8);
}

// ---------- K2: per-pixel GroupNorm (G=32, 8 ch/group), write hn (B, m~=w*64+h, C) bf16 ----------
__global__ __launch_bounds__(256) void gn_kernel(const float* __restrict__ x,
    const float* __restrict__ gnw, const float* __restrict__ gnb,
    short* __restrict__ hn)
{
    int flat = blockIdx.x * 256 + threadIdx.x;
    int n = flat & 4095, g = (flat >> 12) & 31, b = flat >> 17;
    const float* xp = x + (size_t)(b * 256 + g * 8) * 4096 + n;
    float v[8], s = 0.f, s2 = 0.f;
    #pragma unroll
    for (int k = 0; k < 8; k++){ float t = xp[(size_t)k * 4096]; v[k] = t; s += t; s2 += t * t; }
    float mean = s * 0.125f;
    float var  = s2 * 0.125f - mean * mean;
    float inv  = rsqrtf(var + 1e-6f);
    int h = n >> 6, w = n & 63, m = w * 64 + h;
    short o[8];
    #pragma unroll
    for (int k = 0; k < 8; k++)
        o[k] = f2bf((v[k] - mean) * inv * gnw[g * 8 + k] + gnb[g * 8 + k]);
    *(short8_t*)(hn + (size_t)(b * 4096 + m) * 256 + g * 8) = *(short8_t*)o;
}

// ---------- K3: QKV GEMM. Q row-major (pre-scaled 1/16); K,V fragment-major. ----------
// Kf[(b,kb64,kc,ks,lane,8)]: lane holds key kc*16+(lane&15), ch ks*32+(lane>>4)*8+j.
// Vf2[(b,kbd,kc,cht,lane,8)]: lane holds ch cht*16+(lane&15); j<4: key kbd*128+kc*16+(lane>>4)*4+j,
//                             j>=4: key kbd*128+64+kc*16+(lane>>4)*4+(j-4).  (K=32 PV permutation)
__global__ __launch_bounds__(256) void qkv_gemm(const short* __restrict__ hn,
    const short* __restrict__ wT, const float* __restrict__ bq,
    const float* __restrict__ bk, const float* __restrict__ bv,
    short* __restrict__ Q, short* __restrict__ Kf, short* __restrict__ Vf)
{
    __shared__ short As[64 * 72];
    __shared__ short Bs[64 * 72];
    __shared__ float CT[64 * 65];

    const int tid = threadIdx.x;
    const int m0 = blockIdx.x * 64;
    const int by = blockIdx.y;
    const int mat = by >> 2;                 // 0=Q 1=K 2=V
    const int d0 = (by & 3) * 64;
    const short* w = wT + mat * 65536;
    const float* bias = mat == 0 ? bq : mat == 1 ? bk : bv;

    const int wv = tid >> 6, lane = tid & 63;
    const int wrow = (wv >> 1) * 32, wcol = (wv & 1) * 32;
    const int lrow = lane & 15, lq = lane >> 4;

    f32x4 acc[2][2] = {};

    for (int k0 = 0; k0 < 256; k0 += 64){
        __syncthreads();
        #pragma unroll
        for (int i = 0; i < 2; i++){
            int idx = tid + i * 256, r = idx >> 3, c = (idx & 7) * 8;
            *(short8_t*)&As[r * 72 + c] = *(const short8_t*)(hn + (size_t)(m0 + r) * 256 + k0 + c);
            *(short8_t*)&Bs[r * 72 + c] = *(const short8_t*)(w  + (size_t)(d0 + r) * 256 + k0 + c);
        }
        __syncthreads();
        #pragma unroll
        for (int kk = 0; kk < 2; kk++){
            int off = kk * 32 + lq * 8;
            short8_t a0  = *(short8_t*)&As[(wrow + lrow) * 72 + off];
            short8_t a1  = *(short8_t*)&As[(wrow + 16 + lrow) * 72 + off];
            short8_t b0v = *(short8_t*)&Bs[(wcol + lrow) * 72 + off];
            short8_t b1v = *(short8_t*)&Bs[(wcol + 16 + lrow) * 72 + off];
            acc[0][0] = mfma16(a0, b0v, acc[0][0]);
            acc[0][1] = mfma16(a0, b1v, acc[0][1]);
            acc[1][0] = mfma16(a1, b0v, acc[1][0]);
            acc[1][1] = mfma16(a1, b1v, acc[1][1]);
        }
    }

    const int b = m0 >> 12, kb64 = (m0 & 4095) >> 6;

    if (mat == 0){
        #pragma unroll
        for (int i = 0; i < 2; i++)
          #pragma unroll
          for (int j = 0; j < 2; j++)
            #pragma unroll
            for (int r = 0; r < 4; r++){
                int row = wrow + i * 16 + lq * 4 + r;
                int col = wcol + j * 16 + lrow;
                Q[(size_t)(m0 + row) * 256 + d0 + col] = f2bf((acc[i][j][r] + bias[d0 + col]) * 0.0625f);
            }
    } else if (mat == 1){
        // CT[key][ch]
        #pragma unroll
        for (int i = 0; i < 2; i++)
          #pragma unroll
          for (int j = 0; j < 2; j++)
            #pragma unroll
            for (int r = 0; r < 4; r++){
                int row = wrow + i * 16 + lq * 4 + r;
                int col = wcol + j * 16 + lrow;
                CT[row * 65 + col] = acc[i][j][r] + bias[d0 + col];
            }
        __syncthreads();
        int key = tid >> 2, c16 = (tid & 3) * 16;
        int kc = key >> 4, l15 = key & 15;
        #pragma unroll
        for (int half = 0; half < 2; half++){
            int ch0 = c16 + half * 8;
            int ks = (d0 + ch0) >> 5, lqf = (ch0 & 31) >> 3;
            short tmp[8];
            #pragma unroll
            for (int j = 0; j < 8; j++) tmp[j] = f2bf(CT[key * 65 + ch0 + j]);
            size_t base = ((((size_t)(b * 64 + kb64)) * 4 + kc) * 8 + ks) * 512 + (lqf * 16 + l15) * 8;
            *(short8_t*)(Kf + base) = *(short8_t*)tmp;
        }
    } else {
        // CT[ch][key]
        #pragma unroll
        for (int i = 0; i < 2; i++)
          #pragma unroll
          for (int j = 0; j < 2; j++)
            #pragma unroll
            for (int r = 0; r < 4; r++){
                int row = wrow + i * 16 + lq * 4 + r;
                int col = wcol + j * 16 + lrow;
                CT[col * 65 + row] = acc[i][j][r] + bias[d0 + col];
            }
        __syncthreads();
        const int kbd = kb64 >> 1, parity = kb64 & 1;
        const int cht_l = tid >> 6, lane_s = tid & 63;
        const int l15s = lane_s & 15, lg4s = lane_s >> 4;
        const int cht = (d0 >> 4) + cht_l;
        #pragma unroll
        for (int kc = 0; kc < 4; kc++){
            short tmp[4];
            #pragma unroll
            for (int j = 0; j < 4; j++)
                tmp[j] = f2bf(CT[(cht_l * 16 + l15s) * 65 + kc * 16 + lg4s * 4 + j]);
            size_t base = (size_t)b * 1048576 + (size_t)kbd * 32768 + kc * 8192
                        + cht * 512 + lane_s * 8 + parity * 4;
            *(short4_t*)(Vf + base) = *(short4_t*)tmp;
        }
    }
}

// ---------- K4: barrier-free flash attention, merged pair-softmax, bf16 combine ----------
// 1024 blocks of 256 threads (4 waves). Each wave runs an independent online-softmax
// chain over its 16-key strips (S^T: stats per lane-column), O^T over all 256 ch.
// NOTE: do NOT bound below 2 waves/EU — live state is ~112 VGPRs (oacc16+qf+kcur+knext);
// a 128-VGPR cap (launch_bounds ,4) spills accumulators to scratch (R9: 627 MB writes).
__global__ __launch_bounds__(256, 2) void attn_kernel(const short* __restrict__ Q,
    const short* __restrict__ Kf, const short* __restrict__ Vf,
    short* __restrict__ hb)
{
    __shared__ float mls[4][16][2];
    __shared__ short LOs[4][16][264];    // [kc][q][ch] bf16, padded (33 KB)

    const int tid = threadIdx.x, lane = tid & 63, kc = tid >> 6;
    const int l15 = lane & 15, lg4 = lane >> 4;
    const int a32 = ((lane ^ 32) << 2);

    const int id = blockIdx.x;
    const int qd = id >> 8, c = id & 255;
    const int w6 = c >> 2, hh = (c >> 1) & 1, rg = c & 1;
    const int b  = qd;
    const int w  = (qd & 1) ? 63 - w6 : w6;
    const int q0 = w * 64 + hh * 32 + rg * 16;

    const short* Kb = Kf + (size_t)b * 1048576 + kc * 4096 + lane * 8;   // +kb*16384 +ks*512
    const short* Vb = Vf + (size_t)b * 1048576 + kc * 8192 + lane * 8;   // +kbd*32768 +cht*512

    // Q as B-fragment (pre-scaled): lane holds Q[q0+l15][ks*32+lg4*8 ..+8]
    short8_t qf[8];
    {
        const short* qp = Q + ((size_t)b * 4096 + q0 + l15) * 256;
        #pragma unroll
        for (int ks = 0; ks < 8; ks++)
            qf[ks] = *(const short8_t*)(qp + ks * 32 + lg4 * 8);
    }

    f32x4 oacc[16] = {};                 // O^T partial: 16 ch-tiles x f32x4
    float m_run = -1e30f, l_run = 0.f;

    short8_t kcur[8], knext[8];
    #pragma unroll
    for (int ks = 0; ks < 8; ks++)
        kcur[ks] = *(const short8_t*)(Kb + ks * 512);

    for (int kb = 0; kb <= w; kb += 2){
        const bool has_odd = (kb + 1 <= w);
        if (has_odd){
            const short* kit = Kb + (size_t)(kb + 1) * 16384;
            #pragma unroll
            for (int ks = 0; ks < 8; ks++)
                knext[ks] = *(const short8_t*)(kit + ks * 512);
        }
        // even strip: S^T = K (A) x Q (B)
        f32x4 st = {};
        #pragma unroll
        for (int ks = 0; ks < 8; ks++) st = mfma16(kcur[ks], qf[ks], st);

        // refill kcur for next pair (after st consumed kcur)
        if (kb + 2 <= w){
            const short* kit = Kb + (size_t)(kb + 2) * 16384;
            #pragma unroll
            for (int ks = 0; ks < 8; ks++)
                kcur[ks] = *(const short8_t*)(kit + ks * 512);
        }

        // odd strip (independent MFMA chain -> ILP with even)
        f32x4 st2 = { -1e30f, -1e30f, -1e30f, -1e30f };
        if (has_odd){
            f32x4 z = {};
            #pragma unroll
            for (int ks = 0; ks < 8; ks++) z = mfma16(knext[ks], qf[ks], z);
            st2 = z;
        }

        // ONE merged softmax update for the 32-key pair
        float tmax = fmaxf(fmaxf(fmaxf(st[0], st[1]), fmaxf(st[2], st[3])),
                           fmaxf(fmaxf(st2[0], st2[1]), fmaxf(st2[2], st2[3])));
        tmax = fmaxf(tmax, swz16(tmax));
        tmax = fmaxf(tmax, bperm32(a32, tmax));
        float m_new = fmaxf(m_run, tmax);
        float alpha = exp2f((m_run - m_new) * LOG2E);
        m_run = m_new;

        f32x4 p_e, p_o;
        #pragma unroll
        for (int r = 0; r < 4; r++){
            p_e[r] = exp2f((st[r]  - m_new) * LOG2E);
            p_o[r] = exp2f((st2[r] - m_new) * LOG2E);
        }
        float tsum = ((p_e[0] + p_e[1]) + (p_e[2] + p_e[3]))
                   + ((p_o[0] + p_o[1]) + (p_o[2] + p_o[3]));
        tsum += swz16(tsum);
        tsum += bperm32(a32, tsum);
        l_run = l_run * alpha + tsum;

        // pack P^T pair as B-fragment (K=32, key-permuted to match Vf2)
        short pb[8];
        #pragma unroll
        for (int r = 0; r < 4; r++){ pb[r] = f2bf(p_e[r]); pb[4 + r] = f2bf(p_o[r]); }
        short8_t pbf = *(short8_t*)pb;

        // PV: O^T[cht] = alpha*O^T[cht] + V^T-frag x P^T
        const short* vit = Vb + (size_t)(kb >> 1) * 32768;
        #pragma unroll
        for (int cht = 0; cht < 16; cht++){
            short8_t vfr = *(const short8_t*)(vit + cht * 512);
            f32x4 t = oacc[cht];
            #pragma unroll
            for (int r = 0; r < 4; r++) t[r] *= alpha;
            oacc[cht] = mfma16(vfr, pbf, t);
        }
    }

    // ---- combine the 4 kc partials ----
    if (lg4 == 0){ mls[kc][l15][0] = m_run; mls[kc][l15][1] = l_run; }
    __syncthreads();
    float m0v = mls[0][l15][0], m1v = mls[1][l15][0], m2v = mls[2][l15][0], m3v = mls[3][l15][0];
    float mstar = fmaxf(fmaxf(m0v, m1v), fmaxf(m2v, m3v));
    float Lsum = mls[0][l15][1] * exp2f((m0v - mstar) * LOG2E)
               + mls[1][l15][1] * exp2f((m1v - mstar) * LOG2E)
               + mls[2][l15][1] * exp2f((m2v - mstar) * LOG2E)
               + mls[3][l15][1] * exp2f((m3v - mstar) * LOG2E);
    float sc = exp2f((m_run - mstar) * LOG2E);
    #pragma unroll
    for (int cht = 0; cht < 16; cht++){
        short t4[4];
        #pragma unroll
        for (int r = 0; r < 4; r++) t4[r] = f2bf(oacc[cht][r] * sc);
        *(short4_t*)&LOs[kc][l15][cht * 16 + lg4 * 4] = *(short4_t*)t4;
    }
    __syncthreads();
    // sum across kc; wave kc handles ch quarter kc*64..+64; lane: q=l15, ch0=kc*64+lg4*16
    {
        const int ch0 = kc * 64 + lg4 * 16;
        float inv = 1.f / Lsum;
        short tmp[16];
        #pragma unroll
        for (int c8 = 0; c8 < 2; c8++){
            short8_t a0 = *(const short8_t*)&LOs[0][l15][ch0 + c8 * 8];
            short8_t a1 = *(const short8_t*)&LOs[1][l15][ch0 + c8 * 8];
            short8_t a2 = *(const short8_t*)&LOs[2][l15][ch0 + c8 * 8];
            short8_t a3 = *(const short8_t*)&LOs[3][l15][ch0 + c8 * 8];
            #pragma unroll
            for (int j = 0; j < 8; j++){
                float s = (bf2f(a0[j]) + bf2f(a1[j])) + (bf2f(a2[j]) + bf2f(a3[j]));
                tmp[c8 * 8 + j] = f2bf(s * inv);
            }
        }
        const int h = hh * 32 + rg * 16 + l15;
        short* dst = hb + ((size_t)b * 4096 + h * 64 + w) * 256 + ch0;
        *(short8_t*)dst = *(short8_t*)tmp;
        *(short8_t*)(dst + 8) = *(short8_t*)(tmp + 8);
    }
}

// ---------- K5: final proj + bias + residual, coalesced f32 store to (B,C,H,W) ----------
__global__ __launch_bounds__(256) void final_gemm(const short* __restrict__ hbuf,
    const short* __restrict__ wT3, const float* __restrict__ b3,
    const float* __restrict__ x, float* __restrict__ out)
{
    __shared__ short As[64 * 72];
    __shared__ short Bs[64 * 72];
    __shared__ float CT[64 * 65];

    const int tid = threadIdx.x;
    const int m0 = blockIdx.x * 64;
    const int d0 = blockIdx.y * 64;
    const int wv = tid >> 6, lane = tid & 63;
    const int wrow = (wv >> 1) * 32, wcol = (wv & 1) * 32;
    const int lrow = lane & 15, lq = lane >> 4;

    f32x4 acc[2][2] = {};
    for (int k0 = 0; k0 < 256; k0 += 64){
        __syncthreads();
        #pragma unroll
        for (int i = 0; i < 2; i++){
            int idx = tid + i * 256, r = idx >> 3, c = (idx & 7) * 8;
            *(short8_t*)&As[r * 72 + c] = *(const short8_t*)(hbuf + (size_t)(m0 + r) * 256 + k0 + c);
            *(short8_t*)&Bs[r * 72 + c] = *(const short8_t*)(wT3 + (size_t)(d0 + r) * 256 + k0 + c);
        }
        __syncthreads();
        #pragma unroll
        for (int kk = 0; kk < 2; kk++){
            int off = kk * 32 + lq * 8;
            short8_t a0  = *(short8_t*)&As[(wrow + lrow) * 72 + off];
            short8_t a1  = *(short8_t*)&As[(wrow + 16 + lrow) * 72 + off];
            short8_t b0v = *(short8_t*)&Bs[(wcol + lrow) * 72 + off];
            short8_t b1v = *(short8_t*)&Bs[(wcol + 16 + lrow) * 72 + off];
            acc[0][0] = mfma16(a0, b0v, acc[0][0]);
            acc[0][1] = mfma16(a0, b1v, acc[0][1]);
            acc[1][0] = mfma16(a1, b0v, acc[1][0]);
            acc[1][1] = mfma16(a1, b1v, acc[1][1]);
        }
    }
    #pragma unroll
    for (int i = 0; i < 2; i++)
      #pragma unroll
      for (int j = 0; j < 2; j++)
        #pragma unroll
        for (int r = 0; r < 4; r++){
            int row = wrow + i * 16 + lq * 4 + r;
            int col = wcol + j * 16 + lrow;
            CT[col * 65 + row] = acc[i][j][r] + b3[d0 + col];
        }
    __syncthreads();
    int b = m0 >> 12, n0 = m0 & 4095, hrow = n0 >> 6;
    int dr = tid >> 2, wc = (tid & 3) * 16;
    size_t base = ((size_t)(b * 256 + d0 + dr) * 64 + hrow) * 64 + wc;
    const f32x4* xp = (const f32x4*)(x + base);
    f32x4* op = (f32x4*)(out + base);
    #pragma unroll
    for (int q = 0; q < 4; q++){
        f32x4 xv = xp[q], o;
        #pragma unroll
        for (int j = 0; j < 4; j++) o[j] = xv[j] + CT[dr * 65 + wc + q * 4 + j];
        op[q] = o;
    }
}

extern "C" void kernel_launch(void* const* d_in, const int* in_sizes, int n_in,
                              void* d_out, int out_size, void* d_ws, size_t ws_size,
                              hipStream_t stream)
{
    const float* x   = (const float*)d_in[0];
    const float* gnw = (const float*)d_in[1];
    const float* gnb = (const float*)d_in[2];
    const float* w0  = (const float*)d_in[3];
    const float* b0  = (const float*)d_in[4];
    const float* w1  = (const float*)d_in[5];
    const float* b1  = (const float*)d_in[6];
    const float* w2  = (const float*)d_in[7];
    const float* b2  = (const float*)d_in[8];
    const float* w3  = (const float*)d_in[9];
    const float* b3  = (const float*)d_in[10];
    float* out = (float*)d_out;

    char* ws = (char*)d_ws;
    short* wT  = (short*)(ws);                  // 512 KB
    short* hn  = (short*)(ws + 524288);         // 8 MB
    short* Qb  = (short*)(ws + 8912896);        // 8 MB
    short* Kfb = (short*)(ws + 17301504);       // frag-major K, 8 MB
    short* Vfb = (short*)(ws + 25690112);       // frag-major V (K=32 perm), 8 MB
    short* hb  = (short*)(ws + 34078720);       // (B, n, C) 8 MB

    prep_w   <<<64, 256, 0, stream>>>(w0, w1, w2, w3, wT);
    gn_kernel<<<2048, 256, 0, stream>>>(x, gnw, gnb, hn);
    qkv_gemm <<<dim3(256, 12), 256, 0, stream>>>(hn, wT, b0, b1, b2, Qb, Kfb, Vfb);
    attn_kernel<<<1024, 256, 0, stream>>>(Qb, Kfb, Vfb, hb);
    final_gemm<<<dim3(256, 4), 256, 0, stream>>>(hb, wT + 3 * 65536, b3, x, out);
}